// Round 10
// baseline (730.873 us; speedup 1.0000x reference)
//
#include <hip/hip_runtime.h>

#define BSZ_  4
#define SEQ_  1024
#define NH_   32
#define NKVH_ 8
#define HD_   128
#define DIM_  4096
#define NTOK_ (BSZ_ * SEQ_)   // 4096 tokens
#define QKVW_ 6144            // fused QKV output width (u16 elems per token)

typedef float  floatx4  __attribute__((ext_vector_type(4)));
typedef float  floatx16 __attribute__((ext_vector_type(16)));
typedef __bf16 bf16x8   __attribute__((ext_vector_type(8)));
typedef unsigned short ushortx8 __attribute__((ext_vector_type(8)));
typedef unsigned int   uint4v   __attribute__((ext_vector_type(4)));

__device__ __forceinline__ float fast_exp2(float x) {
  return __builtin_amdgcn_exp2f(x);   // v_exp_f32 (computes 2^x natively)
}

__device__ __forceinline__ unsigned short f2bf_bits(float f) {
  unsigned int u = __float_as_uint(f);
  u += 0x7FFFu + ((u >> 16) & 1u);   // round-to-nearest-even
  return (unsigned short)(u >> 16);
}
__device__ __forceinline__ unsigned int pack_bf2_rne(float lo, float hi_) {
  return (unsigned int)f2bf_bits(lo) | ((unsigned int)f2bf_bits(hi_) << 16);
}
// truncating pack of two fp32 -> bf16x2 (one v_perm_b32)
__device__ __forceinline__ unsigned int pack_bf2_trunc(float lo, float hi_) {
  return __builtin_amdgcn_perm(__float_as_uint(hi_), __float_as_uint(lo), 0x07060302u);
}

// async global->LDS, 16B per lane; LDS dest = wave-uniform base + lane*16
__device__ __forceinline__ void gld16(const void* g, void* l) {
  __builtin_amdgcn_global_load_lds(
      (const __attribute__((address_space(1))) void*)g,
      (__attribute__((address_space(3))) void*)l, 16, 0, 0);
}

// ---------------------------------------------------------------------------
// fp32 -> bf16 convert (contiguous).
// ---------------------------------------------------------------------------
__global__ __launch_bounds__(256)
void xconv(const float* __restrict__ X, unsigned short* __restrict__ XB)
{
  size_t i = ((size_t)blockIdx.x * 256 + threadIdx.x) * 4;
  float4 v = *(const float4*)&X[i];
  ushort4 o;
  o.x = f2bf_bits(v.x); o.y = f2bf_bits(v.y);
  o.z = f2bf_bits(v.z); o.w = f2bf_bits(v.w);
  *(ushort4*)&XB[i] = o;
}

// ---------------------------------------------------------------------------
// Fused weight transpose-convert for wq|wk|wv: W[4096][Nsrc] fp32 ->
// WT[6144][4096] bf16 (rows 0..4095 wq, 4096..5119 wk, 5120..6143 wv).
// 32x32 tiles; source boundaries are 32-aligned so each block hits one src.
// ---------------------------------------------------------------------------
__global__ __launch_bounds__(256)
void wtrans3(const float* __restrict__ wq, const float* __restrict__ wk,
             const float* __restrict__ wv, unsigned short* __restrict__ WT)
{
  __shared__ unsigned short T[32][36];
  const int n0 = blockIdx.x * 32;     // fused output row base (0..6143)
  const int k0 = blockIdx.y * 32;
  const float* W; int ns0, Nsrc;
  if (n0 < 4096)      { W = wq; ns0 = n0;        Nsrc = 4096; }
  else if (n0 < 5120) { W = wk; ns0 = n0 - 4096; Nsrc = 1024; }
  else                { W = wv; ns0 = n0 - 5120; Nsrc = 1024; }
  const int t = threadIdx.x;
  {
    int kr = t >> 3, nc = (t & 7) * 4;
    float4 v = *(const float4*)&W[(size_t)(k0 + kr) * Nsrc + ns0 + nc];
    T[kr][nc + 0] = f2bf_bits(v.x);
    T[kr][nc + 1] = f2bf_bits(v.y);
    T[kr][nc + 2] = f2bf_bits(v.z);
    T[kr][nc + 3] = f2bf_bits(v.w);
  }
  __syncthreads();
  {
    int nr = t >> 3, kc = (t & 7) * 4;
    ushort4 o;
    o.x = T[kc + 0][nr]; o.y = T[kc + 1][nr];
    o.z = T[kc + 2][nr]; o.w = T[kc + 3][nr];
    *(ushort4*)&WT[(size_t)(n0 + nr) * DIM_ + k0 + kc] = o;
  }
}

// ---------------------------------------------------------------------------
// Weight transpose-convert (single matrix, used for wo): W[K][N] fp32 ->
// WT[N][K] bf16. 32x32 tiles.
// ---------------------------------------------------------------------------
__global__ __launch_bounds__(256)
void wtrans(const float* __restrict__ W, unsigned short* __restrict__ WT,
            int K, int N)
{
  __shared__ unsigned short T[32][36];
  const int k0 = blockIdx.y * 32, n0 = blockIdx.x * 32;
  const int t = threadIdx.x;
  {
    int kr = t >> 3, nc = (t & 7) * 4;
    float4 v = *(const float4*)&W[(size_t)(k0 + kr) * N + n0 + nc];
    T[kr][nc + 0] = f2bf_bits(v.x);
    T[kr][nc + 1] = f2bf_bits(v.y);
    T[kr][nc + 2] = f2bf_bits(v.z);
    T[kr][nc + 3] = f2bf_bits(v.w);
  }
  __syncthreads();
  {
    int nr = t >> 3, kc = (t & 7) * 4;
    ushort4 o;
    o.x = T[kc + 0][nr]; o.y = T[kc + 1][nr];
    o.z = T[kc + 2][nr]; o.w = T[kc + 3][nr];
    *(ushort4*)&WT[(size_t)(n0 + nr) * K + k0 + kc] = o;
  }
}

// ---------------------------------------------------------------------------
// V transpose from fused qkv buffer: qkv[tok][5120 + kvh*128 + d] ->
// VT[(b*8+kvh)*128 + d][1024 s]. 32x32 tiles. grid = (SEQ/32, HD/32, B*NKVH)
// ---------------------------------------------------------------------------
__global__ __launch_bounds__(256)
void vtrans2(const unsigned short* __restrict__ qkv, unsigned short* __restrict__ VT)
{
  __shared__ unsigned short T[32][36];
  const int bh = blockIdx.z;                 // b*8+kvh
  const int s0 = blockIdx.x * 32, d0 = blockIdx.y * 32;
  const int b = bh >> 3, kvh = bh & 7;
  const int t = threadIdx.x;
  {
    int sr = t >> 3, dc = (t & 7) * 4;
    ushort4 v = *(const ushort4*)&qkv[(size_t)(b * SEQ_ + s0 + sr) * QKVW_ + 5120 + kvh * HD_ + d0 + dc];
    T[sr][dc + 0] = v.x; T[sr][dc + 1] = v.y;
    T[sr][dc + 2] = v.z; T[sr][dc + 3] = v.w;
  }
  __syncthreads();
  {
    int dr = t >> 3, sc = (t & 7) * 4;
    ushort4 o;
    o.x = T[sc + 0][dr]; o.y = T[sc + 1][dr];
    o.z = T[sc + 2][dr]; o.w = T[sc + 3][dr];
    *(ushort4*)&VT[((size_t)bh * HD_ + d0 + dr) * SEQ_ + s0 + sc] = o;
  }
}

// ---------------------------------------------------------------------------
// RoPE in place, fused Q+K in one launch. Linear index covers Q pairs
// (NTOK_*2048 u32) then K pairs (NTOK_*512 u32 at base 2048).
// ---------------------------------------------------------------------------
__global__ __launch_bounds__(256)
void rope_all(unsigned int* __restrict__ t, const float* __restrict__ cosf,
              const float* __restrict__ sinf)
{
  int idx = blockIdx.x * 256 + threadIdx.x;
  const int NQ = NTOK_ * 2048;
  int tok, rem, base;
  if (idx < NQ) { tok = idx >> 11; rem = idx & 2047; base = 0; }
  else { int j = idx - NQ; tok = j >> 9; rem = j & 511; base = 2048; }
  int d2  = rem & 63;
  int pos = tok & (SEQ_ - 1);
  unsigned int* p = &t[(size_t)tok * 3072 + base + rem];
  unsigned int pv = *p;
  float xe = __uint_as_float(pv << 16);
  float xo = __uint_as_float(pv & 0xFFFF0000u);
  float cv = cosf[pos * 64 + d2];
  float sv = sinf[pos * 64 + d2];
  float oe = xe * cv - xo * sv;
  float oo = xe * sv + xo * cv;
  *p = pack_bf2_rne(oe, oo);
}

// ---------------------------------------------------------------------------
// GEMM w16 (round-7 structure, best measured: 215.4 us QKV, MfmaUtil 43).
// 256x256x32 tile, 16 waves (1024 thr, 4M x 4N), per-wave 64x64.
// LDS: 4-deep ring x [256][32] per operand = 128 KiB, 1 block/CU.
// ONE barrier per K-tile:
//   { ds_read 8 frags(t) | stage(t+3): 1 A + 1 B gld16 (block-wide 16KB each)
//     | setprio(1) 16 MFMA setprio(0) | s_waitcnt vmcnt(4) | s_barrier }
// Ring-4 WAR + vmcnt(4) counted-depth proof as in R7.
// T2 chunk-XOR swizzle (c ^= (row>>1)&3) both-sides; T1 XCD swizzle.
// ---------------------------------------------------------------------------
template<bool OUT_BF16>
__global__ __launch_bounds__(1024, 4)
void gemm_w16(const unsigned short* __restrict__ A,   // [M][K] bf16
              const unsigned short* __restrict__ B,   // [N][K] bf16
              void* __restrict__ Cout, int M, int N, int K)
{
  __shared__ __align__(16) unsigned short As[4][256][32];
  __shared__ __align__(16) unsigned short Bs[4][256][32];

  const int tid  = threadIdx.x;
  const int w    = tid >> 6;      // 0..15
  const int lane = tid & 63;
  const int l16  = lane & 15;
  const int quad = lane >> 4;
  const int wr   = w >> 2;        // 0..3  (M)
  const int wc   = w & 3;         // 0..3  (N)

  // T1: XCD-aware swizzle (gridDim.x % 8 == 0 at both call sites)
  int wg = blockIdx.x;
  const int q8 = gridDim.x >> 3;
  wg = (wg & 7) * q8 + (wg >> 3);
  const int nbx = N >> 8;
  const int bm = (wg / nbx) * 256;
  const int bn = (wg % nbx) * 256;

  // staging: thread -> row tid>>2 (0..255), chunk tid&3; one block-wide
  // gld16 covers a full 256x32 operand tile (1024 lanes x 16B = 16 KiB).
  const int srow = tid >> 2;
  const int scs  = (tid & 3) ^ ((srow >> 1) & 3);
  const unsigned short* Ag = &A[(size_t)(bm + srow) * K + scs * 8];
  const unsigned short* Bg = &B[(size_t)(bn + srow) * K + scs * 8];
  char* AsW = (char*)&As[0][0][0] + w * 1024;   // + buf*16384
  char* BsW = (char*)&Bs[0][0][0] + w * 1024;

  const int ntiles = K >> 5;   // 128 for K=4096

  auto stage = [&](int kt, int buf) {
    size_t ko = (size_t)kt << 5;
    gld16(Ag + ko, AsW + buf * 16384);
    gld16(Bg + ko, BsW + buf * 16384);
  };

  floatx4 acc[4][4];
#pragma unroll
  for (int i = 0; i < 4; i++)
#pragma unroll
    for (int j = 0; j < 4; j++) acc[i][j] = (floatx4){0.f, 0.f, 0.f, 0.f};

  // fragment-read swizzle: row = 64*wr|wc + 16*i + l16 -> (row>>1)&3 = (l16>>1)&3
  const int cfr = quad ^ ((l16 >> 1) & 3);
  const unsigned short* ArF = &As[0][wr * 64][cfr * 8];
  const unsigned short* BrF = &Bs[0][wc * 64][cfr * 8];

  // ---- prologue: stage tiles 0,1,2; tile 0 landed at vmcnt(4)
  stage(0, 0); stage(1, 1); stage(2, 2);
  asm volatile("s_waitcnt vmcnt(4)" ::: "memory");
  __builtin_amdgcn_s_barrier();

#pragma unroll 1
  for (int t = 0; t < ntiles; t++) {
    const int buf = t & 3;

    bf16x8 af[4], bfr[4];
    {
      const unsigned short* Ab = ArF + (size_t)buf * (256 * 32) + l16 * 32;
      const unsigned short* Bb = BrF + (size_t)buf * (256 * 32) + l16 * 32;
#pragma unroll
      for (int i = 0; i < 4; i++) af[i]  = *(const bf16x8*)&Ab[i * (16 * 32)];
#pragma unroll
      for (int j = 0; j < 4; j++) bfr[j] = *(const bf16x8*)&Bb[j * (16 * 32)];
    }

    {
      int pk = (t + 3 < ntiles) ? t + 3 : 0;
      stage(pk, (t + 3) & 3);
    }

    __builtin_amdgcn_s_setprio(1);
#pragma unroll
    for (int i = 0; i < 4; i++)
#pragma unroll
      for (int j = 0; j < 4; j++)
        acc[i][j] = __builtin_amdgcn_mfma_f32_16x16x32_bf16(af[i], bfr[j], acc[i][j], 0, 0, 0);
    __builtin_amdgcn_s_setprio(0);

    asm volatile("s_waitcnt vmcnt(4)" ::: "memory");
    __builtin_amdgcn_s_barrier();
  }

  asm volatile("s_waitcnt vmcnt(0)" ::: "memory");   // drain dummy tail stages

  // ---- epilogue: C write
#pragma unroll
  for (int i = 0; i < 4; i++)
#pragma unroll
    for (int j = 0; j < 4; j++)
#pragma unroll
      for (int r = 0; r < 4; r++) {
        size_t row = bm + wr * 64 + i * 16 + quad * 4 + r;
        size_t col = bn + wc * 64 + j * 16 + l16;
        if (OUT_BF16)
          ((unsigned short*)Cout)[row * N + col] = f2bf_bits(acc[i][j][r]);
        else
          ((float*)Cout)[row * N + col] = acc[i][j][r];
      }
}

// ---------------------------------------------------------------------------
// Flash attention v2 (GQA, causal): S^T = K Q^T via mfma_32x32x16 so softmax
// is per-lane-column; O^T = V^T P^T. Block = 256 q of one (b,h); 4 waves x
// 64 q; K-tiles of 64 keys.
//
// Round-10 change: JOINT PV. Both q-subtiles' packed P stay in registers
// (pkt[2][2][8], t2 loop unrolled -> static indices); PV runs once after
// both softmaxes so each V fragment is read from LDS ONCE and feeds both
// t2 MFMAs. PV V-reads per wave-tile: 32 -> 16 (LDS pipe was co-bottleneck
// with MFMA). oa[t2] rescale stays inside its t2 iteration (before PV).
// (kept: T12 permlane P-exchange, T14 async-STAGE, T13 defer-max, LPT grid,
// T5 setprio.)
// ---------------------------------------------------------------------------
__global__ __launch_bounds__(256, 2)
void flash_attn2(const unsigned short* __restrict__ qkv,
                 const unsigned short* __restrict__ vt,
                 unsigned short* __restrict__ o)
{
  __shared__ __align__(16) unsigned short S_[4][8192];  // 64 KiB total
  unsigned short* Ks = &S_[0][0];            // [64 key][128 d], chunk-swizzled ^ (key&15)
  unsigned short* Vs = &S_[1][0];            // [128 d][64 key], chunk-swizzled ^ (d&7)
  // S_[2..3] unused in main loop; whole S_ reused as per-wave patch in epilogue

  // ---- LPT remap: grp 0->qt3, 1->qt2, 2->qt0, 3->qt1
  const int bid = blockIdx.x;
  const int grp = bid >> 7;
  const int idx = bid & 127;
  const int qt = (grp == 0) ? 3 : (grp == 1) ? 2 : (grp == 2) ? 0 : 1;
  const int h = idx & 31, b = idx >> 5;

  const int kvh = h >> 2;
  const int tid = threadIdx.x, w = tid >> 6, lane = tid & 63;
  const int l31 = lane & 31, hi = lane >> 5;
  const int qb = qt * 256, qw = qb + w * 64;

  const float CEXP = (float)(0.08838834764831845 * 1.4426950408889634); // scale*log2(e)

  // ---- Q fragments in registers (B-operand layout: n=l31, k=hi*8+j per 16-k step)
  bf16x8 qf[2][8];
#pragma unroll
  for (int t2 = 0; t2 < 2; t2++) {
    const unsigned short* qrow =
        &qkv[(size_t)(b * SEQ_ + qw + t2 * 32 + l31) * QKVW_ + h * HD_ + hi * 8];
#pragma unroll
    for (int s = 0; s < 8; s++)
      qf[t2][s] = *(const bf16x8*)&qrow[s * 16];
  }

  floatx16 oa[2][4];   // O^T accumulators: [q-subtile][d-tile], col=q=l31
#pragma unroll
  for (int t2 = 0; t2 < 2; t2++)
#pragma unroll
    for (int dt = 0; dt < 4; dt++)
#pragma unroll
      for (int r = 0; r < 16; r++) oa[t2][dt][r] = 0.f;

  float ms[2] = {-3.0e38f, -3.0e38f};  // running max, SCALED (log2) units
  float ls[2] = {0.f, 0.f};

  const int nk = qb + 256;
  const int qmaxw = qw + 63;

  // ---- T14 staging state: next tile's K/V in registers (32 VGPR)
  ushortx8 kreg[4], vreg[4];
  const size_t kg0 = (size_t)(b * SEQ_) * QKVW_ + 4096 + kvh * HD_;
  const size_t vg0 = ((size_t)(b * NKVH_ + kvh) * HD_) * SEQ_;
  const int krow = tid >> 4, kc = tid & 15;        // K: covers 16 keys/iter
  const int vrow = tid >> 3, vc = tid & 7;         // V: covers 32 d/iter

  auto issue_loads = [&](int kb) {
    const size_t gb = kg0 + (size_t)kb * QKVW_;
#pragma unroll
    for (int it = 0; it < 4; it++)
      kreg[it] = *(const ushortx8*)&qkv[gb + (size_t)(it * 16 + krow) * QKVW_ + kc * 8];
    const size_t vb = vg0 + kb;
#pragma unroll
    for (int it = 0; it < 4; it++)
      vreg[it] = *(const ushortx8*)&vt[vb + (size_t)(it * 32 + vrow) * SEQ_ + vc * 8];
  };
  auto write_lds = [&]() {
#pragma unroll
    for (int it = 0; it < 4; it++) {
      int key = it * 16 + krow;
      *(ushortx8*)&Ks[key * 128 + ((kc ^ (key & 15)) * 8)] = kreg[it];
    }
#pragma unroll
    for (int it = 0; it < 4; it++) {
      int d = it * 32 + vrow;
      *(ushortx8*)&Vs[d * 64 + ((vc ^ (d & 7)) * 8)] = vreg[it];
    }
  };

  issue_loads(0);

  for (int kb_ = 0; kb_ < nk; kb_ += 64) {
    __syncthreads();   // WAR: all readers of previous tile done (drains vmcnt
                       // for the prefetch we are about to consume -- desired)
    write_lds();
    if (kb_ + 64 < nk) issue_loads(kb_ + 64);   // prefetch under compute
    asm volatile("s_waitcnt lgkmcnt(0)" ::: "memory");   // ds_writes visible
    __builtin_amdgcn_s_barrier();                        // loads stay in flight

    if (kb_ <= qmaxw) {                      // wave has >=1 unmasked key in tile
      const bool needmask = (kb_ + 63 > qw);
      unsigned int pkt[2][2][8];             // [t2][k2][word], all idx static

#pragma unroll
      for (int t2 = 0; t2 < 2; t2++) {
        // ---- S^T = K @ Q^T : two 32-key C-tiles, rows=keys, cols=queries
        floatx16 sc[2];
#pragma unroll
        for (int r = 0; r < 16; r++) { sc[0][r] = 0.f; sc[1][r] = 0.f; }
        __builtin_amdgcn_s_setprio(1);
#pragma unroll
        for (int s = 0; s < 8; s++) {
          int c = 2 * s + hi;
          bf16x8 k0 = *(const bf16x8*)&Ks[l31 * 128 + ((c ^ (l31 & 15)) * 8)];
          bf16x8 k1 = *(const bf16x8*)&Ks[(32 + l31) * 128 + ((c ^ ((32 + l31) & 15)) * 8)];
          sc[0] = __builtin_amdgcn_mfma_f32_32x32x16_bf16(k0, qf[t2][s], sc[0], 0, 0, 0);
          sc[1] = __builtin_amdgcn_mfma_f32_32x32x16_bf16(k1, qf[t2][s], sc[1], 0, 0, 0);
        }
        __builtin_amdgcn_s_setprio(0);

        // ---- causal mask (row = key = (r&3)+8*(r>>2)+4*hi; col = q = l31)
        if (needmask) {
          const int q = qw + t2 * 32 + l31;
#pragma unroll
          for (int k2 = 0; k2 < 2; k2++)
#pragma unroll
            for (int r = 0; r < 16; r++) {
              int key = kb_ + k2 * 32 + (r & 3) + 8 * (r >> 2) + 4 * hi;
              if (key > q) sc[k2][r] = -3.0e38f;
            }
        }

        // ---- online softmax for this lane's query (32 vals in-lane + xor32)
        float mx0 = sc[0][0], mx1 = sc[0][1];
#pragma unroll
        for (int r = 2; r < 16; r += 2) { mx0 = fmaxf(mx0, sc[0][r]); mx1 = fmaxf(mx1, sc[0][r + 1]); }
#pragma unroll
        for (int r = 0; r < 16; r += 2) { mx0 = fmaxf(mx0, sc[1][r]); mx1 = fmaxf(mx1, sc[1][r + 1]); }
        float mx = fmaxf(mx0, mx1);
        mx = fmaxf(mx, __shfl_xor(mx, 32));
        float mxs = mx * CEXP;

        // ---- T13 defer-max: keep old max unless growth > 8 (P <= 2^8)
        float mn, alpha;
        if (__all(mxs - ms[t2] <= 8.0f)) {
          mn = ms[t2]; alpha = 1.0f;
        } else {
          mn = fmaxf(ms[t2], mxs);
          alpha = fast_exp2(ms[t2] - mn);
          ms[t2] = mn;
        }

        // ---- exp + pack P into registers (key pairs per u32)
        float rs0 = 0.f, rs1 = 0.f;
#pragma unroll
        for (int k2 = 0; k2 < 2; k2++) {
#pragma unroll
          for (int r = 0; r < 16; r += 2) {
            float p0 = fast_exp2(__builtin_fmaf(sc[k2][r],     CEXP, -mn));
            float p1 = fast_exp2(__builtin_fmaf(sc[k2][r + 1], CEXP, -mn));
            rs0 += p0; rs1 += p1;
            pkt[t2][k2][r >> 1] = pack_bf2_trunc(p0, p1);
          }
        }
        float rs = rs0 + rs1;
        rs += __shfl_xor(rs, 32);
        ls[t2] = ls[t2] * alpha + rs;

        if (__any(alpha != 1.0f)) {
#pragma unroll
          for (int dt = 0; dt < 4; dt++)
#pragma unroll
            for (int r = 0; r < 16; r++) oa[t2][dt][r] *= alpha;
        }
      }

      // ---- JOINT PV: each V fragment read once, feeds both q-subtiles
      __builtin_amdgcn_s_setprio(1);
#pragma unroll
      for (int ks = 0; ks < 4; ks++) {
        const int k2s = ks >> 1;
        const int sub = (ks & 1) * 4;
        bf16x8 pf0, pf1;
        {
          auto w02 = __builtin_amdgcn_permlane32_swap(pkt[0][k2s][sub + 0], pkt[0][k2s][sub + 2], false, false);
          auto w13 = __builtin_amdgcn_permlane32_swap(pkt[0][k2s][sub + 1], pkt[0][k2s][sub + 3], false, false);
          uint4v pw = (uint4v){(unsigned int)w02[0], (unsigned int)w13[0],
                               (unsigned int)w02[1], (unsigned int)w13[1]};
          pf0 = __builtin_bit_cast(bf16x8, pw);
        }
        {
          auto w02 = __builtin_amdgcn_permlane32_swap(pkt[1][k2s][sub + 0], pkt[1][k2s][sub + 2], false, false);
          auto w13 = __builtin_amdgcn_permlane32_swap(pkt[1][k2s][sub + 1], pkt[1][k2s][sub + 3], false, false);
          uint4v pw = (uint4v){(unsigned int)w02[0], (unsigned int)w13[0],
                               (unsigned int)w02[1], (unsigned int)w13[1]};
          pf1 = __builtin_bit_cast(bf16x8, pw);
        }
        int c = 2 * ks + hi;
#pragma unroll
        for (int dt = 0; dt < 4; dt++) {
          int d = dt * 32 + l31;
          bf16x8 vf = *(const bf16x8*)&Vs[d * 64 + ((c ^ (d & 7)) * 8)];
          oa[0][dt] = __builtin_amdgcn_mfma_f32_32x32x16_bf16(vf, pf0, oa[0][dt], 0, 0, 0);
          oa[1][dt] = __builtin_amdgcn_mfma_f32_32x32x16_bf16(vf, pf1, oa[1][dt], 0, 0, 0);
        }
      }
      __builtin_amdgcn_s_setprio(0);
    }
  }

  // ---- epilogue: normalize, transpose O^T -> O rows via per-wave LDS patch
  __syncthreads();                 // everyone done reading Ks/Vs
  unsigned short* patch = &S_[w][0];   // [64 q][128 d], chunk-swizzled ^ (q&7)
  float inv[2] = {1.0f / ls[0], 1.0f / ls[1]};
#pragma unroll
  for (int t2 = 0; t2 < 2; t2++) {
    const int qloc = t2 * 32 + l31;
#pragma unroll
    for (int dt = 0; dt < 4; dt++)
#pragma unroll
      for (int rq = 0; rq < 4; rq++) {
        float a0 = oa[t2][dt][rq * 4 + 0] * inv[t2];
        float a1 = oa[t2][dt][rq * 4 + 1] * inv[t2];
        float a2 = oa[t2][dt][rq * 4 + 2] * inv[t2];
        float a3 = oa[t2][dt][rq * 4 + 3] * inv[t2];
        int doff = dt * 32 + 8 * rq + 4 * hi;
        int c = doff >> 3;
        uint2 val = {pack_bf2_rne(a0, a1), pack_bf2_rne(a2, a3)};
        *(uint2*)&patch[qloc * 128 + ((c ^ (qloc & 7)) * 8) + (doff & 7)] = val;
      }
  }
  // in-wave: write -> read dependency handled by compiler waitcnt
#pragma unroll
  for (int it = 0; it < 16; it++) {
    int idx2 = it * 64 + lane;
    int row = idx2 >> 4, c = idx2 & 15;
    int cc = (c & 7) ^ (row & 7);
    int cs = (c & 8) | cc;          // swizzle only low 3 bits (mask was &7)
    ushortx8 vv = *(const ushortx8*)&patch[row * 128 + cs * 8];
    *(ushortx8*)&o[(size_t)(b * SEQ_ + qb + w * 64 + row) * 4096 + h * HD_ + c * 8] = vv;
  }
}

// ---------------------------------------------------------------------------
extern "C" void kernel_launch(void* const* d_in, const int* in_sizes, int n_in,
                              void* d_out, int out_size, void* d_ws, size_t ws_size,
                              hipStream_t stream)
{
  const float* x  = (const float*)d_in[0];
  const float* wq = (const float*)d_in[1];
  const float* wk = (const float*)d_in[2];
  const float* wv = (const float*)d_in[3];
  const float* wo = (const float*)d_in[4];
  const float* fc = (const float*)d_in[5];
  const float* fs = (const float*)d_in[6];
  float* out = (float*)d_out;

  // bf16 workspace layout (2B elems): total 136 MB
  unsigned short* xb    = (unsigned short*)d_ws;                 // 4096x4096 (32MB), reused as ab
  unsigned short* wqkvT = xb    + (size_t)NTOK_ * DIM_;          // 6144x4096 (48MB), reused as woT
  unsigned short* qkvb  = wqkvT + (size_t)QKVW_ * DIM_;          // 4096x6144 (48MB)
  unsigned short* vtb   = qkvb  + (size_t)NTOK_ * QKVW_;         // 8x128x... (8MB)
  unsigned short* ab    = xb;    // alias: xb dead after QKV proj
  unsigned short* woT   = wqkvT; // alias: wqkvT dead after QKV proj

  dim3 blk(256);

  xconv<<<(NTOK_ * DIM_ / 4) / 256, blk, 0, stream>>>(x, xb);
  // fused wq|wk|wv transpose-convert into wqkvT [6144][4096]
  wtrans3<<<dim3(QKVW_ / 32, DIM_ / 32), blk, 0, stream>>>(wq, wk, wv, wqkvT);

  // fused QKV projection: [4096 tok][6144] bf16 -- 256x256 tiles, 24x16 = 384 wgs
  gemm_w16<true><<<dim3((QKVW_ / 256) * (NTOK_ / 256)), dim3(1024), 0, stream>>>(
      xb, wqkvT, qkvb, NTOK_, QKVW_, DIM_);

  wtrans<<<dim3(DIM_ / 32, DIM_ / 32), blk, 0, stream>>>(wo, woT, DIM_, DIM_);  // aliases wqkvT: after QKV GEMM

  // RoPE on Q (2048 u32/token) and K (512 u32/token at base 2048), one launch
  rope_all<<<(NTOK_ * 2560) / 256, blk, 0, stream>>>((unsigned int*)qkvb, fc, fs);

  vtrans2<<<dim3(SEQ_ / 32, HD_ / 32, BSZ_ * NKVH_), blk, 0, stream>>>(qkvb, vtb);

  // flash attention: 1-D LPT-ordered grid (512 blocks)
  flash_attn2<<<dim3((SEQ_ / 256) * NH_ * BSZ_), blk, 0, stream>>>(qkvb, vtb, ab);

  // output projection: 256x256 tiles, 16x16 = 256 wgs (perfect packing)
  gemm_w16<false><<<dim3((DIM_ / 256) * (NTOK_ / 256)), dim3(1024), 0, stream>>>(
      ab, woT, out, NTOK_, DIM_, DIM_);
}

// Round 11
// 682.531 us; speedup vs baseline: 1.0708x; 1.0708x over previous
//
#include <hip/hip_runtime.h>

#define BSZ_  4
#define SEQ_  1024
#define NH_   32
#define NKVH_ 8
#define HD_   128
#define DIM_  4096
#define NTOK_ (BSZ_ * SEQ_)   // 4096 tokens
#define QKVW_ 6144            // fused QKV output width (u16 elems per token)

typedef float  floatx4  __attribute__((ext_vector_type(4)));
typedef float  floatx16 __attribute__((ext_vector_type(16)));
typedef __bf16 bf16x8   __attribute__((ext_vector_type(8)));
typedef unsigned short ushortx8 __attribute__((ext_vector_type(8)));
typedef unsigned int   uint4v   __attribute__((ext_vector_type(4)));

__device__ __forceinline__ float fast_exp2(float x) {
  return __builtin_amdgcn_exp2f(x);   // v_exp_f32 (computes 2^x natively)
}

__device__ __forceinline__ unsigned short f2bf_bits(float f) {
  unsigned int u = __float_as_uint(f);
  u += 0x7FFFu + ((u >> 16) & 1u);   // round-to-nearest-even
  return (unsigned short)(u >> 16);
}
__device__ __forceinline__ unsigned int pack_bf2_rne(float lo, float hi_) {
  return (unsigned int)f2bf_bits(lo) | ((unsigned int)f2bf_bits(hi_) << 16);
}
// truncating pack of two fp32 -> bf16x2 (one v_perm_b32)
__device__ __forceinline__ unsigned int pack_bf2_trunc(float lo, float hi_) {
  return __builtin_amdgcn_perm(__float_as_uint(hi_), __float_as_uint(lo), 0x07060302u);
}

// async global->LDS, 16B per lane; LDS dest = wave-uniform base + lane*16
__device__ __forceinline__ void gld16(const void* g, void* l) {
  __builtin_amdgcn_global_load_lds(
      (const __attribute__((address_space(1))) void*)g,
      (__attribute__((address_space(3))) void*)l, 16, 0, 0);
}

// ---------------------------------------------------------------------------
// fp32 -> bf16 convert (contiguous).
// ---------------------------------------------------------------------------
__global__ __launch_bounds__(256)
void xconv(const float* __restrict__ X, unsigned short* __restrict__ XB)
{
  size_t i = ((size_t)blockIdx.x * 256 + threadIdx.x) * 4;
  float4 v = *(const float4*)&X[i];
  ushort4 o;
  o.x = f2bf_bits(v.x); o.y = f2bf_bits(v.y);
  o.z = f2bf_bits(v.z); o.w = f2bf_bits(v.w);
  *(ushort4*)&XB[i] = o;
}

// ---------------------------------------------------------------------------
// Fused weight transpose-convert for wq|wk|wv: W[4096][Nsrc] fp32 ->
// WT[6144][4096] bf16 (rows 0..4095 wq, 4096..5119 wk, 5120..6143 wv).
// 32x32 tiles; source boundaries are 32-aligned so each block hits one src.
// ---------------------------------------------------------------------------
__global__ __launch_bounds__(256)
void wtrans3(const float* __restrict__ wq, const float* __restrict__ wk,
             const float* __restrict__ wv, unsigned short* __restrict__ WT)
{
  __shared__ unsigned short T[32][36];
  const int n0 = blockIdx.x * 32;     // fused output row base (0..6143)
  const int k0 = blockIdx.y * 32;
  const float* W; int ns0, Nsrc;
  if (n0 < 4096)      { W = wq; ns0 = n0;        Nsrc = 4096; }
  else if (n0 < 5120) { W = wk; ns0 = n0 - 4096; Nsrc = 1024; }
  else                { W = wv; ns0 = n0 - 5120; Nsrc = 1024; }
  const int t = threadIdx.x;
  {
    int kr = t >> 3, nc = (t & 7) * 4;
    float4 v = *(const float4*)&W[(size_t)(k0 + kr) * Nsrc + ns0 + nc];
    T[kr][nc + 0] = f2bf_bits(v.x);
    T[kr][nc + 1] = f2bf_bits(v.y);
    T[kr][nc + 2] = f2bf_bits(v.z);
    T[kr][nc + 3] = f2bf_bits(v.w);
  }
  __syncthreads();
  {
    int nr = t >> 3, kc = (t & 7) * 4;
    ushort4 o;
    o.x = T[kc + 0][nr]; o.y = T[kc + 1][nr];
    o.z = T[kc + 2][nr]; o.w = T[kc + 3][nr];
    *(ushort4*)&WT[(size_t)(n0 + nr) * DIM_ + k0 + kc] = o;
  }
}

// ---------------------------------------------------------------------------
// Weight transpose-convert (single matrix, used for wo): W[K][N] fp32 ->
// WT[N][K] bf16. 32x32 tiles.
// ---------------------------------------------------------------------------
__global__ __launch_bounds__(256)
void wtrans(const float* __restrict__ W, unsigned short* __restrict__ WT,
            int K, int N)
{
  __shared__ unsigned short T[32][36];
  const int k0 = blockIdx.y * 32, n0 = blockIdx.x * 32;
  const int t = threadIdx.x;
  {
    int kr = t >> 3, nc = (t & 7) * 4;
    float4 v = *(const float4*)&W[(size_t)(k0 + kr) * N + n0 + nc];
    T[kr][nc + 0] = f2bf_bits(v.x);
    T[kr][nc + 1] = f2bf_bits(v.y);
    T[kr][nc + 2] = f2bf_bits(v.z);
    T[kr][nc + 3] = f2bf_bits(v.w);
  }
  __syncthreads();
  {
    int nr = t >> 3, kc = (t & 7) * 4;
    ushort4 o;
    o.x = T[kc + 0][nr]; o.y = T[kc + 1][nr];
    o.z = T[kc + 2][nr]; o.w = T[kc + 3][nr];
    *(ushort4*)&WT[(size_t)(n0 + nr) * K + k0 + kc] = o;
  }
}

// ---------------------------------------------------------------------------
// V transpose from fused qkv buffer: qkv[tok][5120 + kvh*128 + d] ->
// VT[(b*8+kvh)*128 + d][1024 s]. 32x32 tiles. grid = (SEQ/32, HD/32, B*NKVH)
// ---------------------------------------------------------------------------
__global__ __launch_bounds__(256)
void vtrans2(const unsigned short* __restrict__ qkv, unsigned short* __restrict__ VT)
{
  __shared__ unsigned short T[32][36];
  const int bh = blockIdx.z;                 // b*8+kvh
  const int s0 = blockIdx.x * 32, d0 = blockIdx.y * 32;
  const int b = bh >> 3, kvh = bh & 7;
  const int t = threadIdx.x;
  {
    int sr = t >> 3, dc = (t & 7) * 4;
    ushort4 v = *(const ushort4*)&qkv[(size_t)(b * SEQ_ + s0 + sr) * QKVW_ + 5120 + kvh * HD_ + d0 + dc];
    T[sr][dc + 0] = v.x; T[sr][dc + 1] = v.y;
    T[sr][dc + 2] = v.z; T[sr][dc + 3] = v.w;
  }
  __syncthreads();
  {
    int dr = t >> 3, sc = (t & 7) * 4;
    ushort4 o;
    o.x = T[sc + 0][dr]; o.y = T[sc + 1][dr];
    o.z = T[sc + 2][dr]; o.w = T[sc + 3][dr];
    *(ushort4*)&VT[((size_t)bh * HD_ + d0 + dr) * SEQ_ + s0 + sc] = o;
  }
}

// ---------------------------------------------------------------------------
// RoPE in place, fused Q+K in one launch. Linear index covers Q pairs
// (NTOK_*2048 u32) then K pairs (NTOK_*512 u32 at base 2048).
// ---------------------------------------------------------------------------
__global__ __launch_bounds__(256)
void rope_all(unsigned int* __restrict__ t, const float* __restrict__ cosf,
              const float* __restrict__ sinf)
{
  int idx = blockIdx.x * 256 + threadIdx.x;
  const int NQ = NTOK_ * 2048;
  int tok, rem, base;
  if (idx < NQ) { tok = idx >> 11; rem = idx & 2047; base = 0; }
  else { int j = idx - NQ; tok = j >> 9; rem = j & 511; base = 2048; }
  int d2  = rem & 63;
  int pos = tok & (SEQ_ - 1);
  unsigned int* p = &t[(size_t)tok * 3072 + base + rem];
  unsigned int pv = *p;
  float xe = __uint_as_float(pv << 16);
  float xo = __uint_as_float(pv & 0xFFFF0000u);
  float cv = cosf[pos * 64 + d2];
  float sv = sinf[pos * 64 + d2];
  float oe = xe * cv - xo * sv;
  float oo = xe * sv + xo * cv;
  *p = pack_bf2_rne(oe, oo);
}

// ---------------------------------------------------------------------------
// GEMM w16 (round-7 structure, best measured: 215.4 us QKV, MfmaUtil 43).
// 256x256x32 tile, 16 waves (1024 thr, 4M x 4N), per-wave 64x64.
// LDS: 4-deep ring x [256][32] per operand = 128 KiB, 1 block/CU.
// ONE barrier per K-tile:
//   { ds_read 8 frags(t) | stage(t+3): 1 A + 1 B gld16 (block-wide 16KB each)
//     | setprio(1) 16 MFMA setprio(0) | s_waitcnt vmcnt(4) | s_barrier }
// Ring-4 WAR + vmcnt(4) counted-depth proof as in R7.
// T2 chunk-XOR swizzle (c ^= (row>>1)&3) both-sides; T1 XCD swizzle.
// ---------------------------------------------------------------------------
template<bool OUT_BF16>
__global__ __launch_bounds__(1024, 4)
void gemm_w16(const unsigned short* __restrict__ A,   // [M][K] bf16
              const unsigned short* __restrict__ B,   // [N][K] bf16
              void* __restrict__ Cout, int M, int N, int K)
{
  __shared__ __align__(16) unsigned short As[4][256][32];
  __shared__ __align__(16) unsigned short Bs[4][256][32];

  const int tid  = threadIdx.x;
  const int w    = tid >> 6;      // 0..15
  const int lane = tid & 63;
  const int l16  = lane & 15;
  const int quad = lane >> 4;
  const int wr   = w >> 2;        // 0..3  (M)
  const int wc   = w & 3;         // 0..3  (N)

  // T1: XCD-aware swizzle (gridDim.x % 8 == 0 at both call sites)
  int wg = blockIdx.x;
  const int q8 = gridDim.x >> 3;
  wg = (wg & 7) * q8 + (wg >> 3);
  const int nbx = N >> 8;
  const int bm = (wg / nbx) * 256;
  const int bn = (wg % nbx) * 256;

  // staging: thread -> row tid>>2 (0..255), chunk tid&3; one block-wide
  // gld16 covers a full 256x32 operand tile (1024 lanes x 16B = 16 KiB).
  const int srow = tid >> 2;
  const int scs  = (tid & 3) ^ ((srow >> 1) & 3);
  const unsigned short* Ag = &A[(size_t)(bm + srow) * K + scs * 8];
  const unsigned short* Bg = &B[(size_t)(bn + srow) * K + scs * 8];
  char* AsW = (char*)&As[0][0][0] + w * 1024;   // + buf*16384
  char* BsW = (char*)&Bs[0][0][0] + w * 1024;

  const int ntiles = K >> 5;   // 128 for K=4096

  auto stage = [&](int kt, int buf) {
    size_t ko = (size_t)kt << 5;
    gld16(Ag + ko, AsW + buf * 16384);
    gld16(Bg + ko, BsW + buf * 16384);
  };

  floatx4 acc[4][4];
#pragma unroll
  for (int i = 0; i < 4; i++)
#pragma unroll
    for (int j = 0; j < 4; j++) acc[i][j] = (floatx4){0.f, 0.f, 0.f, 0.f};

  // fragment-read swizzle: row = 64*wr|wc + 16*i + l16 -> (row>>1)&3 = (l16>>1)&3
  const int cfr = quad ^ ((l16 >> 1) & 3);
  const unsigned short* ArF = &As[0][wr * 64][cfr * 8];
  const unsigned short* BrF = &Bs[0][wc * 64][cfr * 8];

  // ---- prologue: stage tiles 0,1,2; tile 0 landed at vmcnt(4)
  stage(0, 0); stage(1, 1); stage(2, 2);
  asm volatile("s_waitcnt vmcnt(4)" ::: "memory");
  __builtin_amdgcn_s_barrier();

#pragma unroll 1
  for (int t = 0; t < ntiles; t++) {
    const int buf = t & 3;

    bf16x8 af[4], bfr[4];
    {
      const unsigned short* Ab = ArF + (size_t)buf * (256 * 32) + l16 * 32;
      const unsigned short* Bb = BrF + (size_t)buf * (256 * 32) + l16 * 32;
#pragma unroll
      for (int i = 0; i < 4; i++) af[i]  = *(const bf16x8*)&Ab[i * (16 * 32)];
#pragma unroll
      for (int j = 0; j < 4; j++) bfr[j] = *(const bf16x8*)&Bb[j * (16 * 32)];
    }

    {
      int pk = (t + 3 < ntiles) ? t + 3 : 0;
      stage(pk, (t + 3) & 3);
    }

    __builtin_amdgcn_s_setprio(1);
#pragma unroll
    for (int i = 0; i < 4; i++)
#pragma unroll
      for (int j = 0; j < 4; j++)
        acc[i][j] = __builtin_amdgcn_mfma_f32_16x16x32_bf16(af[i], bfr[j], acc[i][j], 0, 0, 0);
    __builtin_amdgcn_s_setprio(0);

    asm volatile("s_waitcnt vmcnt(4)" ::: "memory");
    __builtin_amdgcn_s_barrier();
  }

  asm volatile("s_waitcnt vmcnt(0)" ::: "memory");   // drain dummy tail stages

  // ---- epilogue: C write
#pragma unroll
  for (int i = 0; i < 4; i++)
#pragma unroll
    for (int j = 0; j < 4; j++)
#pragma unroll
      for (int r = 0; r < 4; r++) {
        size_t row = bm + wr * 64 + i * 16 + quad * 4 + r;
        size_t col = bn + wc * 64 + j * 16 + l16;
        if (OUT_BF16)
          ((unsigned short*)Cout)[row * N + col] = f2bf_bits(acc[i][j][r]);
        else
          ((float*)Cout)[row * N + col] = acc[i][j][r];
      }
}

// ---------------------------------------------------------------------------
// Flash attention v2 (GQA, causal) -- EXACT round-9 version (677.8 us wall).
// S^T = K Q^T via mfma_32x32x16 so softmax is per-lane-column; O^T = V^T P^T.
// Block = 256 q of one (b,h); 4 waves x 64 q; K-tiles of 64 keys.
// T12: P never touches LDS -- per-t2 pk2[2][8] consumed immediately by PV
// inside the t2 loop (keeps pk2 live only while sc is dead -> no spill;
// R10's joint-PV variant kept both t2 sets live and spilled, -53 us).
// (T14 async-STAGE, T13 defer-max, LPT grid pairing, T5 setprio.)
// ---------------------------------------------------------------------------
__global__ __launch_bounds__(256, 2)
void flash_attn2(const unsigned short* __restrict__ qkv,
                 const unsigned short* __restrict__ vt,
                 unsigned short* __restrict__ o)
{
  __shared__ __align__(16) unsigned short S_[4][8192];  // 64 KiB total
  unsigned short* Ks = &S_[0][0];            // [64 key][128 d], chunk-swizzled ^ (key&15)
  unsigned short* Vs = &S_[1][0];            // [128 d][64 key], chunk-swizzled ^ (d&7)
  // S_[2..3] unused in main loop; whole S_ reused as per-wave patch in epilogue

  // ---- LPT remap: grp 0->qt3, 1->qt2, 2->qt0, 3->qt1
  const int bid = blockIdx.x;
  const int grp = bid >> 7;
  const int idx = bid & 127;
  const int qt = (grp == 0) ? 3 : (grp == 1) ? 2 : (grp == 2) ? 0 : 1;
  const int h = idx & 31, b = idx >> 5;

  const int kvh = h >> 2;
  const int tid = threadIdx.x, w = tid >> 6, lane = tid & 63;
  const int l31 = lane & 31, hi = lane >> 5;
  const int qb = qt * 256, qw = qb + w * 64;

  const float CEXP = (float)(0.08838834764831845 * 1.4426950408889634); // scale*log2(e)

  // ---- Q fragments in registers (B-operand layout: n=l31, k=hi*8+j per 16-k step)
  bf16x8 qf[2][8];
#pragma unroll
  for (int t2 = 0; t2 < 2; t2++) {
    const unsigned short* qrow =
        &qkv[(size_t)(b * SEQ_ + qw + t2 * 32 + l31) * QKVW_ + h * HD_ + hi * 8];
#pragma unroll
    for (int s = 0; s < 8; s++)
      qf[t2][s] = *(const bf16x8*)&qrow[s * 16];
  }

  floatx16 oa[2][4];   // O^T accumulators: [q-subtile][d-tile], col=q=l31
#pragma unroll
  for (int t2 = 0; t2 < 2; t2++)
#pragma unroll
    for (int dt = 0; dt < 4; dt++)
#pragma unroll
      for (int r = 0; r < 16; r++) oa[t2][dt][r] = 0.f;

  float ms[2] = {-3.0e38f, -3.0e38f};  // running max, SCALED (log2) units
  float ls[2] = {0.f, 0.f};

  const int nk = qb + 256;
  const int qmaxw = qw + 63;

  // ---- T14 staging state: next tile's K/V in registers (32 VGPR)
  ushortx8 kreg[4], vreg[4];
  const size_t kg0 = (size_t)(b * SEQ_) * QKVW_ + 4096 + kvh * HD_;
  const size_t vg0 = ((size_t)(b * NKVH_ + kvh) * HD_) * SEQ_;
  const int krow = tid >> 4, kc = tid & 15;        // K: covers 16 keys/iter
  const int vrow = tid >> 3, vc = tid & 7;         // V: covers 32 d/iter

  auto issue_loads = [&](int kb) {
    const size_t gb = kg0 + (size_t)kb * QKVW_;
#pragma unroll
    for (int it = 0; it < 4; it++)
      kreg[it] = *(const ushortx8*)&qkv[gb + (size_t)(it * 16 + krow) * QKVW_ + kc * 8];
    const size_t vb = vg0 + kb;
#pragma unroll
    for (int it = 0; it < 4; it++)
      vreg[it] = *(const ushortx8*)&vt[vb + (size_t)(it * 32 + vrow) * SEQ_ + vc * 8];
  };
  auto write_lds = [&]() {
#pragma unroll
    for (int it = 0; it < 4; it++) {
      int key = it * 16 + krow;
      *(ushortx8*)&Ks[key * 128 + ((kc ^ (key & 15)) * 8)] = kreg[it];
    }
#pragma unroll
    for (int it = 0; it < 4; it++) {
      int d = it * 32 + vrow;
      *(ushortx8*)&Vs[d * 64 + ((vc ^ (d & 7)) * 8)] = vreg[it];
    }
  };

  issue_loads(0);

  for (int kb_ = 0; kb_ < nk; kb_ += 64) {
    __syncthreads();   // WAR: all readers of previous tile done (drains vmcnt
                       // for the prefetch we are about to consume -- desired)
    write_lds();
    if (kb_ + 64 < nk) issue_loads(kb_ + 64);   // prefetch under compute
    asm volatile("s_waitcnt lgkmcnt(0)" ::: "memory");   // ds_writes visible
    __builtin_amdgcn_s_barrier();                        // loads stay in flight

    if (kb_ <= qmaxw) {                      // wave has >=1 unmasked key in tile
      const bool needmask = (kb_ + 63 > qw);

#pragma unroll
      for (int t2 = 0; t2 < 2; t2++) {
        // ---- S^T = K @ Q^T : two 32-key C-tiles, rows=keys, cols=queries
        floatx16 sc[2];
#pragma unroll
        for (int r = 0; r < 16; r++) { sc[0][r] = 0.f; sc[1][r] = 0.f; }
        __builtin_amdgcn_s_setprio(1);
#pragma unroll
        for (int s = 0; s < 8; s++) {
          int c = 2 * s + hi;
          bf16x8 k0 = *(const bf16x8*)&Ks[l31 * 128 + ((c ^ (l31 & 15)) * 8)];
          bf16x8 k1 = *(const bf16x8*)&Ks[(32 + l31) * 128 + ((c ^ ((32 + l31) & 15)) * 8)];
          sc[0] = __builtin_amdgcn_mfma_f32_32x32x16_bf16(k0, qf[t2][s], sc[0], 0, 0, 0);
          sc[1] = __builtin_amdgcn_mfma_f32_32x32x16_bf16(k1, qf[t2][s], sc[1], 0, 0, 0);
        }
        __builtin_amdgcn_s_setprio(0);

        // ---- causal mask (row = key = (r&3)+8*(r>>2)+4*hi; col = q = l31)
        if (needmask) {
          const int q = qw + t2 * 32 + l31;
#pragma unroll
          for (int k2 = 0; k2 < 2; k2++)
#pragma unroll
            for (int r = 0; r < 16; r++) {
              int key = kb_ + k2 * 32 + (r & 3) + 8 * (r >> 2) + 4 * hi;
              if (key > q) sc[k2][r] = -3.0e38f;
            }
        }

        // ---- online softmax for this lane's query (32 vals in-lane + xor32)
        float mx0 = sc[0][0], mx1 = sc[0][1];
#pragma unroll
        for (int r = 2; r < 16; r += 2) { mx0 = fmaxf(mx0, sc[0][r]); mx1 = fmaxf(mx1, sc[0][r + 1]); }
#pragma unroll
        for (int r = 0; r < 16; r += 2) { mx0 = fmaxf(mx0, sc[1][r]); mx1 = fmaxf(mx1, sc[1][r + 1]); }
        float mx = fmaxf(mx0, mx1);
        mx = fmaxf(mx, __shfl_xor(mx, 32));
        float mxs = mx * CEXP;

        // ---- T13 defer-max: keep old max unless growth > 8 (P <= 2^8)
        float mn, alpha;
        if (__all(mxs - ms[t2] <= 8.0f)) {
          mn = ms[t2]; alpha = 1.0f;
        } else {
          mn = fmaxf(ms[t2], mxs);
          alpha = fast_exp2(ms[t2] - mn);
          ms[t2] = mn;
        }

        // ---- exp + pack P into registers (key pairs per u32)
        float rs0 = 0.f, rs1 = 0.f;
        unsigned int pk2[2][8];
#pragma unroll
        for (int k2 = 0; k2 < 2; k2++) {
#pragma unroll
          for (int r = 0; r < 16; r += 2) {
            float p0 = fast_exp2(__builtin_fmaf(sc[k2][r],     CEXP, -mn));
            float p1 = fast_exp2(__builtin_fmaf(sc[k2][r + 1], CEXP, -mn));
            rs0 += p0; rs1 += p1;
            pk2[k2][r >> 1] = pack_bf2_trunc(p0, p1);
          }
        }
        float rs = rs0 + rs1;
        rs += __shfl_xor(rs, 32);
        ls[t2] = ls[t2] * alpha + rs;

        if (__any(alpha != 1.0f)) {
#pragma unroll
          for (int dt = 0; dt < 4; dt++)
#pragma unroll
            for (int r = 0; r < 16; r++) oa[t2][dt][r] *= alpha;
        }

        // ---- PV for this q-subtile: O^T[t2] += V^T @ P^T, P via permlane
        __builtin_amdgcn_s_setprio(1);
#pragma unroll
        for (int ks = 0; ks < 4; ks++) {
          const int k2s = ks >> 1;
          const int sub = (ks & 1) * 4;
          auto w02 = __builtin_amdgcn_permlane32_swap(pk2[k2s][sub + 0], pk2[k2s][sub + 2], false, false);
          auto w13 = __builtin_amdgcn_permlane32_swap(pk2[k2s][sub + 1], pk2[k2s][sub + 3], false, false);
          uint4v pw = (uint4v){(unsigned int)w02[0], (unsigned int)w13[0],
                               (unsigned int)w02[1], (unsigned int)w13[1]};
          bf16x8 pf = __builtin_bit_cast(bf16x8, pw);
          int c = 2 * ks + hi;
#pragma unroll
          for (int dt = 0; dt < 4; dt++) {
            int d = dt * 32 + l31;
            bf16x8 vf = *(const bf16x8*)&Vs[d * 64 + ((c ^ (d & 7)) * 8)];
            oa[t2][dt] = __builtin_amdgcn_mfma_f32_32x32x16_bf16(vf, pf, oa[t2][dt], 0, 0, 0);
          }
        }
        __builtin_amdgcn_s_setprio(0);
      }
    }
  }

  // ---- epilogue: normalize, transpose O^T -> O rows via per-wave LDS patch
  __syncthreads();                 // everyone done reading Ks/Vs
  unsigned short* patch = &S_[w][0];   // [64 q][128 d], chunk-swizzled ^ (q&7)
  float inv[2] = {1.0f / ls[0], 1.0f / ls[1]};
#pragma unroll
  for (int t2 = 0; t2 < 2; t2++) {
    const int qloc = t2 * 32 + l31;
#pragma unroll
    for (int dt = 0; dt < 4; dt++)
#pragma unroll
      for (int rq = 0; rq < 4; rq++) {
        float a0 = oa[t2][dt][rq * 4 + 0] * inv[t2];
        float a1 = oa[t2][dt][rq * 4 + 1] * inv[t2];
        float a2 = oa[t2][dt][rq * 4 + 2] * inv[t2];
        float a3 = oa[t2][dt][rq * 4 + 3] * inv[t2];
        int doff = dt * 32 + 8 * rq + 4 * hi;
        int c = doff >> 3;
        uint2 val = {pack_bf2_rne(a0, a1), pack_bf2_rne(a2, a3)};
        *(uint2*)&patch[qloc * 128 + ((c ^ (qloc & 7)) * 8) + (doff & 7)] = val;
      }
  }
  // in-wave: write -> read dependency handled by compiler waitcnt
#pragma unroll
  for (int it = 0; it < 16; it++) {
    int idx2 = it * 64 + lane;
    int row = idx2 >> 4, c = idx2 & 15;
    int cc = (c & 7) ^ (row & 7);
    int cs = (c & 8) | cc;          // swizzle only low 3 bits (mask was &7)
    ushortx8 vv = *(const ushortx8*)&patch[row * 128 + cs * 8];
    *(ushortx8*)&o[(size_t)(b * SEQ_ + qb + w * 64 + row) * 4096 + h * HD_ + c * 8] = vv;
  }
}

// ---------------------------------------------------------------------------
extern "C" void kernel_launch(void* const* d_in, const int* in_sizes, int n_in,
                              void* d_out, int out_size, void* d_ws, size_t ws_size,
                              hipStream_t stream)
{
  const float* x  = (const float*)d_in[0];
  const float* wq = (const float*)d_in[1];
  const float* wk = (const float*)d_in[2];
  const float* wv = (const float*)d_in[3];
  const float* wo = (const float*)d_in[4];
  const float* fc = (const float*)d_in[5];
  const float* fs = (const float*)d_in[6];
  float* out = (float*)d_out;

  // bf16 workspace layout (2B elems): total 136 MB
  unsigned short* xb    = (unsigned short*)d_ws;                 // 4096x4096 (32MB), reused as ab
  unsigned short* wqkvT = xb    + (size_t)NTOK_ * DIM_;          // 6144x4096 (48MB), reused as woT
  unsigned short* qkvb  = wqkvT + (size_t)QKVW_ * DIM_;          // 4096x6144 (48MB)
  unsigned short* vtb   = qkvb  + (size_t)NTOK_ * QKVW_;         // 8x128x... (8MB)
  unsigned short* ab    = xb;    // alias: xb dead after QKV proj
  unsigned short* woT   = wqkvT; // alias: wqkvT dead after QKV proj

  dim3 blk(256);

  xconv<<<(NTOK_ * DIM_ / 4) / 256, blk, 0, stream>>>(x, xb);
  // fused wq|wk|wv transpose-convert into wqkvT [6144][4096]
  wtrans3<<<dim3(QKVW_ / 32, DIM_ / 32), blk, 0, stream>>>(wq, wk, wv, wqkvT);

  // fused QKV projection: [4096 tok][6144] bf16 -- 256x256 tiles, 24x16 = 384 wgs
  gemm_w16<true><<<dim3((QKVW_ / 256) * (NTOK_ / 256)), dim3(1024), 0, stream>>>(
      xb, wqkvT, qkvb, NTOK_, QKVW_, DIM_);

  wtrans<<<dim3(DIM_ / 32, DIM_ / 32), blk, 0, stream>>>(wo, woT, DIM_, DIM_);  // aliases wqkvT: after QKV GEMM

  // RoPE on Q (2048 u32/token) and K (512 u32/token at base 2048), one launch
  rope_all<<<(NTOK_ * 2560) / 256, blk, 0, stream>>>((unsigned int*)qkvb, fc, fs);

  vtrans2<<<dim3(SEQ_ / 32, HD_ / 32, BSZ_ * NKVH_), blk, 0, stream>>>(qkvb, vtb);

  // flash attention: 1-D LPT-ordered grid (512 blocks)
  flash_attn2<<<dim3((SEQ_ / 256) * NH_ * BSZ_), blk, 0, stream>>>(qkvb, vtb, ab);

  // output projection: 256x256 tiles, 16x16 = 256 wgs (perfect packing)
  gemm_w16<false><<<dim3((DIM_ / 256) * (NTOK_ / 256)), dim3(1024), 0, stream>>>(
      ab, woT, out, NTOK_, DIM_, DIM_);
}

// Round 12
// 658.436 us; speedup vs baseline: 1.1100x; 1.0366x over previous
//
#include <hip/hip_runtime.h>

#define BSZ_  4
#define SEQ_  1024
#define NH_   32
#define NKVH_ 8
#define HD_   128
#define DIM_  4096
#define NTOK_ (BSZ_ * SEQ_)   // 4096 tokens
#define QKVW_ 6144            // fused QKV output width (u16 elems per token)

typedef float  floatx4  __attribute__((ext_vector_type(4)));
typedef float  floatx16 __attribute__((ext_vector_type(16)));
typedef __bf16 bf16x8   __attribute__((ext_vector_type(8)));
typedef unsigned short ushortx8 __attribute__((ext_vector_type(8)));
typedef unsigned int   uint4v   __attribute__((ext_vector_type(4)));

__device__ __forceinline__ float fast_exp2(float x) {
  return __builtin_amdgcn_exp2f(x);   // v_exp_f32 (computes 2^x natively)
}

__device__ __forceinline__ unsigned short f2bf_bits(float f) {
  unsigned int u = __float_as_uint(f);
  u += 0x7FFFu + ((u >> 16) & 1u);   // round-to-nearest-even
  return (unsigned short)(u >> 16);
}
__device__ __forceinline__ unsigned int pack_bf2_rne(float lo, float hi_) {
  return (unsigned int)f2bf_bits(lo) | ((unsigned int)f2bf_bits(hi_) << 16);
}
// truncating pack of two fp32 -> bf16x2 (one v_perm_b32)
__device__ __forceinline__ unsigned int pack_bf2_trunc(float lo, float hi_) {
  return __builtin_amdgcn_perm(__float_as_uint(hi_), __float_as_uint(lo), 0x07060302u);
}

// async global->LDS, 16B per lane; LDS dest = wave-uniform base + lane*16
__device__ __forceinline__ void gld16(const void* g, void* l) {
  __builtin_amdgcn_global_load_lds(
      (const __attribute__((address_space(1))) void*)g,
      (__attribute__((address_space(3))) void*)l, 16, 0, 0);
}

// ---------------------------------------------------------------------------
// Merged prep: region-split grid.
//  blocks [0, 16384): xconv -- fp32 -> bf16 convert of x (4096x4096).
//  blocks [16384, 40960): wtrans3 -- fused wq|wk|wv transpose-convert into
//  WT[6144][4096] bf16 (rows 0..4095 wq, 4096..5119 wk, 5120..6143 wv).
// ---------------------------------------------------------------------------
__global__ __launch_bounds__(256)
void prep(const float* __restrict__ X, unsigned short* __restrict__ XB,
          const float* __restrict__ wq, const float* __restrict__ wk,
          const float* __restrict__ wv, unsigned short* __restrict__ WT)
{
  __shared__ unsigned short T[32][36];
  const int bid = blockIdx.x;
  const int t = threadIdx.x;
  if (bid < 16384) {
    size_t i = ((size_t)bid * 256 + t) * 4;
    float4 v = *(const float4*)&X[i];
    ushort4 o;
    o.x = f2bf_bits(v.x); o.y = f2bf_bits(v.y);
    o.z = f2bf_bits(v.z); o.w = f2bf_bits(v.w);
    *(ushort4*)&XB[i] = o;
    return;
  }
  const int id = bid - 16384;
  const int n0 = (id % 192) * 32;     // fused output row base (0..6143)
  const int k0 = (id / 192) * 32;
  const float* W; int ns0, Nsrc;
  if (n0 < 4096)      { W = wq; ns0 = n0;        Nsrc = 4096; }
  else if (n0 < 5120) { W = wk; ns0 = n0 - 4096; Nsrc = 1024; }
  else                { W = wv; ns0 = n0 - 5120; Nsrc = 1024; }
  {
    int kr = t >> 3, nc = (t & 7) * 4;
    float4 v = *(const float4*)&W[(size_t)(k0 + kr) * Nsrc + ns0 + nc];
    T[kr][nc + 0] = f2bf_bits(v.x);
    T[kr][nc + 1] = f2bf_bits(v.y);
    T[kr][nc + 2] = f2bf_bits(v.z);
    T[kr][nc + 3] = f2bf_bits(v.w);
  }
  __syncthreads();
  {
    int nr = t >> 3, kc = (t & 7) * 4;
    ushort4 o;
    o.x = T[kc + 0][nr]; o.y = T[kc + 1][nr];
    o.z = T[kc + 2][nr]; o.w = T[kc + 3][nr];
    *(ushort4*)&WT[(size_t)(n0 + nr) * DIM_ + k0 + kc] = o;
  }
}

// ---------------------------------------------------------------------------
// Weight transpose-convert (single matrix, used for wo): W[K][N] fp32 ->
// WT[N][K] bf16. 32x32 tiles.
// ---------------------------------------------------------------------------
__global__ __launch_bounds__(256)
void wtrans(const float* __restrict__ W, unsigned short* __restrict__ WT,
            int K, int N)
{
  __shared__ unsigned short T[32][36];
  const int k0 = blockIdx.y * 32, n0 = blockIdx.x * 32;
  const int t = threadIdx.x;
  {
    int kr = t >> 3, nc = (t & 7) * 4;
    float4 v = *(const float4*)&W[(size_t)(k0 + kr) * N + n0 + nc];
    T[kr][nc + 0] = f2bf_bits(v.x);
    T[kr][nc + 1] = f2bf_bits(v.y);
    T[kr][nc + 2] = f2bf_bits(v.z);
    T[kr][nc + 3] = f2bf_bits(v.w);
  }
  __syncthreads();
  {
    int nr = t >> 3, kc = (t & 7) * 4;
    ushort4 o;
    o.x = T[kc + 0][nr]; o.y = T[kc + 1][nr];
    o.z = T[kc + 2][nr]; o.w = T[kc + 3][nr];
    *(ushort4*)&WT[(size_t)(n0 + nr) * K + k0 + kc] = o;
  }
}

// ---------------------------------------------------------------------------
// V transpose from fused qkv buffer: qkv[tok][5120 + kvh*128 + d] ->
// VT[(b*8+kvh)*128 + d][1024 s]. 32x32 tiles. grid = (SEQ/32, HD/32, B*NKVH)
// ---------------------------------------------------------------------------
__global__ __launch_bounds__(256)
void vtrans2(const unsigned short* __restrict__ qkv, unsigned short* __restrict__ VT)
{
  __shared__ unsigned short T[32][36];
  const int bh = blockIdx.z;                 // b*8+kvh
  const int s0 = blockIdx.x * 32, d0 = blockIdx.y * 32;
  const int b = bh >> 3, kvh = bh & 7;
  const int t = threadIdx.x;
  {
    int sr = t >> 3, dc = (t & 7) * 4;
    ushort4 v = *(const ushort4*)&qkv[(size_t)(b * SEQ_ + s0 + sr) * QKVW_ + 5120 + kvh * HD_ + d0 + dc];
    T[sr][dc + 0] = v.x; T[sr][dc + 1] = v.y;
    T[sr][dc + 2] = v.z; T[sr][dc + 3] = v.w;
  }
  __syncthreads();
  {
    int dr = t >> 3, sc = (t & 7) * 4;
    ushort4 o;
    o.x = T[sc + 0][dr]; o.y = T[sc + 1][dr];
    o.z = T[sc + 2][dr]; o.w = T[sc + 3][dr];
    *(ushort4*)&VT[((size_t)bh * HD_ + d0 + dr) * SEQ_ + s0 + sc] = o;
  }
}

// ---------------------------------------------------------------------------
// GEMM w16 (round-7 structure). 256x256x32 tile, 16 waves, per-wave 64x64.
// LDS: 4-deep ring x [256][32] per operand = 128 KiB, 1 block/CU.
// ONE barrier per K-tile; ring-4 WAR + vmcnt(4) counted depth (R7 proof).
// T2 chunk-XOR swizzle both-sides; T1 XCD swizzle.
//
// Round-12: DO_ROPE template flag fuses RoPE into the epilogue for the QKV
// call. The rope region (output cols < 5120 = Q|K) is BLOCK-uniform (bn is a
// multiple of 256; boundary 5120 = 20*256). Pairs (2k,2k+1) sit in adjacent
// lanes (col = ... + l16), so the partner value is __shfl_xor(acc,1); even
// lane writes xe*c - xo*s, odd lane writes xe*s + xo*c, in fp32 BEFORE the
// bf16 round (previously double-rounded via the separate rope pass).
// ---------------------------------------------------------------------------
template<bool OUT_BF16, bool DO_ROPE>
__global__ __launch_bounds__(1024, 4)
void gemm_w16(const unsigned short* __restrict__ A,   // [M][K] bf16
              const unsigned short* __restrict__ B,   // [N][K] bf16
              void* __restrict__ Cout, int M, int N, int K,
              const float* __restrict__ fc, const float* __restrict__ fs)
{
  __shared__ __align__(16) unsigned short As[4][256][32];
  __shared__ __align__(16) unsigned short Bs[4][256][32];

  const int tid  = threadIdx.x;
  const int w    = tid >> 6;      // 0..15
  const int lane = tid & 63;
  const int l16  = lane & 15;
  const int quad = lane >> 4;
  const int wr   = w >> 2;        // 0..3  (M)
  const int wc   = w & 3;         // 0..3  (N)

  // T1: XCD-aware swizzle (gridDim.x % 8 == 0 at both call sites)
  int wg = blockIdx.x;
  const int q8 = gridDim.x >> 3;
  wg = (wg & 7) * q8 + (wg >> 3);
  const int nbx = N >> 8;
  const int bm = (wg / nbx) * 256;
  const int bn = (wg % nbx) * 256;

  // staging: thread -> row tid>>2 (0..255), chunk tid&3; one block-wide
  // gld16 covers a full 256x32 operand tile (1024 lanes x 16B = 16 KiB).
  const int srow = tid >> 2;
  const int scs  = (tid & 3) ^ ((srow >> 1) & 3);
  const unsigned short* Ag = &A[(size_t)(bm + srow) * K + scs * 8];
  const unsigned short* Bg = &B[(size_t)(bn + srow) * K + scs * 8];
  char* AsW = (char*)&As[0][0][0] + w * 1024;   // + buf*16384
  char* BsW = (char*)&Bs[0][0][0] + w * 1024;

  const int ntiles = K >> 5;   // 128 for K=4096

  auto stage = [&](int kt, int buf) {
    size_t ko = (size_t)kt << 5;
    gld16(Ag + ko, AsW + buf * 16384);
    gld16(Bg + ko, BsW + buf * 16384);
  };

  floatx4 acc[4][4];
#pragma unroll
  for (int i = 0; i < 4; i++)
#pragma unroll
    for (int j = 0; j < 4; j++) acc[i][j] = (floatx4){0.f, 0.f, 0.f, 0.f};

  // fragment-read swizzle: row = 64*wr|wc + 16*i + l16 -> (row>>1)&3 = (l16>>1)&3
  const int cfr = quad ^ ((l16 >> 1) & 3);
  const unsigned short* ArF = &As[0][wr * 64][cfr * 8];
  const unsigned short* BrF = &Bs[0][wc * 64][cfr * 8];

  // ---- prologue: stage tiles 0,1,2; tile 0 landed at vmcnt(4)
  stage(0, 0); stage(1, 1); stage(2, 2);
  asm volatile("s_waitcnt vmcnt(4)" ::: "memory");
  __builtin_amdgcn_s_barrier();

#pragma unroll 1
  for (int t = 0; t < ntiles; t++) {
    const int buf = t & 3;

    bf16x8 af[4], bfr[4];
    {
      const unsigned short* Ab = ArF + (size_t)buf * (256 * 32) + l16 * 32;
      const unsigned short* Bb = BrF + (size_t)buf * (256 * 32) + l16 * 32;
#pragma unroll
      for (int i = 0; i < 4; i++) af[i]  = *(const bf16x8*)&Ab[i * (16 * 32)];
#pragma unroll
      for (int j = 0; j < 4; j++) bfr[j] = *(const bf16x8*)&Bb[j * (16 * 32)];
    }

    {
      int pk = (t + 3 < ntiles) ? t + 3 : 0;
      stage(pk, (t + 3) & 3);
    }

    __builtin_amdgcn_s_setprio(1);
#pragma unroll
    for (int i = 0; i < 4; i++)
#pragma unroll
      for (int j = 0; j < 4; j++)
        acc[i][j] = __builtin_amdgcn_mfma_f32_16x16x32_bf16(af[i], bfr[j], acc[i][j], 0, 0, 0);
    __builtin_amdgcn_s_setprio(0);

    asm volatile("s_waitcnt vmcnt(4)" ::: "memory");
    __builtin_amdgcn_s_barrier();
  }

  asm volatile("s_waitcnt vmcnt(0)" ::: "memory");   // drain dummy tail stages

  // ---- epilogue: C write (optionally with fused RoPE for Q|K columns)
  if (DO_ROPE && bn < 5120) {
    const float sgn = (l16 & 1) ? 1.0f : -1.0f;
#pragma unroll
    for (int i = 0; i < 4; i++)
#pragma unroll
      for (int r = 0; r < 4; r++) {
        int row = bm + wr * 64 + i * 16 + quad * 4 + r;
        int pos = row & (SEQ_ - 1);
#pragma unroll
        for (int j = 0; j < 4; j++) {
          int col = bn + wc * 64 + j * 16 + l16;
          int d2 = (col & 127) >> 1;
          float cv = fc[pos * 64 + d2];
          float sv = fs[pos * 64 + d2];
          float val = acc[i][j][r];
          float other = __shfl_xor(val, 1);
          // even lane: xe*c - xo*s ; odd lane: xe*s + xo*c
          float base = (l16 & 1) ? other * sv : val * cv;
          float term = (l16 & 1) ? val * cv   : other * sv;
          float out = __builtin_fmaf(sgn, term, base) ;
          // even: base - term = ... wait: even -> val*cv - other*sv; odd -> other*sv + val*cv
          out = (l16 & 1) ? (other * sv + val * cv) : (val * cv - other * sv);
          ((unsigned short*)Cout)[(size_t)row * N + col] = f2bf_bits(out);
        }
      }
  } else {
#pragma unroll
    for (int i = 0; i < 4; i++)
#pragma unroll
      for (int j = 0; j < 4; j++)
#pragma unroll
        for (int r = 0; r < 4; r++) {
          size_t row = bm + wr * 64 + i * 16 + quad * 4 + r;
          size_t col = bn + wc * 64 + j * 16 + l16;
          if (OUT_BF16)
            ((unsigned short*)Cout)[row * N + col] = f2bf_bits(acc[i][j][r]);
          else
            ((float*)Cout)[row * N + col] = acc[i][j][r];
        }
  }
}

// ---------------------------------------------------------------------------
// Flash attention v2 (GQA, causal) -- EXACT round-9 version (677.8 us wall).
// S^T = K Q^T via mfma_32x32x16 so softmax is per-lane-column; O^T = V^T P^T.
// Block = 256 q of one (b,h); 4 waves x 64 q; K-tiles of 64 keys.
// T12: P never touches LDS -- per-t2 pk2[2][8] consumed immediately by PV
// inside the t2 loop. (T14 async-STAGE, T13 defer-max, LPT grid, T5 setprio.)
// ---------------------------------------------------------------------------
__global__ __launch_bounds__(256, 2)
void flash_attn2(const unsigned short* __restrict__ qkv,
                 const unsigned short* __restrict__ vt,
                 unsigned short* __restrict__ o)
{
  __shared__ __align__(16) unsigned short S_[4][8192];  // 64 KiB total
  unsigned short* Ks = &S_[0][0];            // [64 key][128 d], chunk-swizzled ^ (key&15)
  unsigned short* Vs = &S_[1][0];            // [128 d][64 key], chunk-swizzled ^ (d&7)

  // ---- LPT remap: grp 0->qt3, 1->qt2, 2->qt0, 3->qt1
  const int bid = blockIdx.x;
  const int grp = bid >> 7;
  const int idx = bid & 127;
  const int qt = (grp == 0) ? 3 : (grp == 1) ? 2 : (grp == 2) ? 0 : 1;
  const int h = idx & 31, b = idx >> 5;

  const int kvh = h >> 2;
  const int tid = threadIdx.x, w = tid >> 6, lane = tid & 63;
  const int l31 = lane & 31, hi = lane >> 5;
  const int qb = qt * 256, qw = qb + w * 64;

  const float CEXP = (float)(0.08838834764831845 * 1.4426950408889634); // scale*log2(e)

  // ---- Q fragments in registers (B-operand layout: n=l31, k=hi*8+j per 16-k step)
  bf16x8 qf[2][8];
#pragma unroll
  for (int t2 = 0; t2 < 2; t2++) {
    const unsigned short* qrow =
        &qkv[(size_t)(b * SEQ_ + qw + t2 * 32 + l31) * QKVW_ + h * HD_ + hi * 8];
#pragma unroll
    for (int s = 0; s < 8; s++)
      qf[t2][s] = *(const bf16x8*)&qrow[s * 16];
  }

  floatx16 oa[2][4];   // O^T accumulators: [q-subtile][d-tile], col=q=l31
#pragma unroll
  for (int t2 = 0; t2 < 2; t2++)
#pragma unroll
    for (int dt = 0; dt < 4; dt++)
#pragma unroll
      for (int r = 0; r < 16; r++) oa[t2][dt][r] = 0.f;

  float ms[2] = {-3.0e38f, -3.0e38f};  // running max, SCALED (log2) units
  float ls[2] = {0.f, 0.f};

  const int nk = qb + 256;
  const int qmaxw = qw + 63;

  // ---- T14 staging state: next tile's K/V in registers (32 VGPR)
  ushortx8 kreg[4], vreg[4];
  const size_t kg0 = (size_t)(b * SEQ_) * QKVW_ + 4096 + kvh * HD_;
  const size_t vg0 = ((size_t)(b * NKVH_ + kvh) * HD_) * SEQ_;
  const int krow = tid >> 4, kc = tid & 15;        // K: covers 16 keys/iter
  const int vrow = tid >> 3, vc = tid & 7;         // V: covers 32 d/iter

  auto issue_loads = [&](int kb) {
    const size_t gb = kg0 + (size_t)kb * QKVW_;
#pragma unroll
    for (int it = 0; it < 4; it++)
      kreg[it] = *(const ushortx8*)&qkv[gb + (size_t)(it * 16 + krow) * QKVW_ + kc * 8];
    const size_t vb = vg0 + kb;
#pragma unroll
    for (int it = 0; it < 4; it++)
      vreg[it] = *(const ushortx8*)&vt[vb + (size_t)(it * 32 + vrow) * SEQ_ + vc * 8];
  };
  auto write_lds = [&]() {
#pragma unroll
    for (int it = 0; it < 4; it++) {
      int key = it * 16 + krow;
      *(ushortx8*)&Ks[key * 128 + ((kc ^ (key & 15)) * 8)] = kreg[it];
    }
#pragma unroll
    for (int it = 0; it < 4; it++) {
      int d = it * 32 + vrow;
      *(ushortx8*)&Vs[d * 64 + ((vc ^ (d & 7)) * 8)] = vreg[it];
    }
  };

  issue_loads(0);

  for (int kb_ = 0; kb_ < nk; kb_ += 64) {
    __syncthreads();   // WAR: all readers of previous tile done (drains vmcnt
                       // for the prefetch we are about to consume -- desired)
    write_lds();
    if (kb_ + 64 < nk) issue_loads(kb_ + 64);   // prefetch under compute
    asm volatile("s_waitcnt lgkmcnt(0)" ::: "memory");   // ds_writes visible
    __builtin_amdgcn_s_barrier();                        // loads stay in flight

    if (kb_ <= qmaxw) {                      // wave has >=1 unmasked key in tile
      const bool needmask = (kb_ + 63 > qw);

#pragma unroll
      for (int t2 = 0; t2 < 2; t2++) {
        // ---- S^T = K @ Q^T : two 32-key C-tiles, rows=keys, cols=queries
        floatx16 sc[2];
#pragma unroll
        for (int r = 0; r < 16; r++) { sc[0][r] = 0.f; sc[1][r] = 0.f; }
        __builtin_amdgcn_s_setprio(1);
#pragma unroll
        for (int s = 0; s < 8; s++) {
          int c = 2 * s + hi;
          bf16x8 k0 = *(const bf16x8*)&Ks[l31 * 128 + ((c ^ (l31 & 15)) * 8)];
          bf16x8 k1 = *(const bf16x8*)&Ks[(32 + l31) * 128 + ((c ^ ((32 + l31) & 15)) * 8)];
          sc[0] = __builtin_amdgcn_mfma_f32_32x32x16_bf16(k0, qf[t2][s], sc[0], 0, 0, 0);
          sc[1] = __builtin_amdgcn_mfma_f32_32x32x16_bf16(k1, qf[t2][s], sc[1], 0, 0, 0);
        }
        __builtin_amdgcn_s_setprio(0);

        // ---- causal mask (row = key = (r&3)+8*(r>>2)+4*hi; col = q = l31)
        if (needmask) {
          const int q = qw + t2 * 32 + l31;
#pragma unroll
          for (int k2 = 0; k2 < 2; k2++)
#pragma unroll
            for (int r = 0; r < 16; r++) {
              int key = kb_ + k2 * 32 + (r & 3) + 8 * (r >> 2) + 4 * hi;
              if (key > q) sc[k2][r] = -3.0e38f;
            }
        }

        // ---- online softmax for this lane's query (32 vals in-lane + xor32)
        float mx0 = sc[0][0], mx1 = sc[0][1];
#pragma unroll
        for (int r = 2; r < 16; r += 2) { mx0 = fmaxf(mx0, sc[0][r]); mx1 = fmaxf(mx1, sc[0][r + 1]); }
#pragma unroll
        for (int r = 0; r < 16; r += 2) { mx0 = fmaxf(mx0, sc[1][r]); mx1 = fmaxf(mx1, sc[1][r + 1]); }
        float mx = fmaxf(mx0, mx1);
        mx = fmaxf(mx, __shfl_xor(mx, 32));
        float mxs = mx * CEXP;

        // ---- T13 defer-max: keep old max unless growth > 8 (P <= 2^8)
        float mn, alpha;
        if (__all(mxs - ms[t2] <= 8.0f)) {
          mn = ms[t2]; alpha = 1.0f;
        } else {
          mn = fmaxf(ms[t2], mxs);
          alpha = fast_exp2(ms[t2] - mn);
          ms[t2] = mn;
        }

        // ---- exp + pack P into registers (key pairs per u32)
        float rs0 = 0.f, rs1 = 0.f;
        unsigned int pk2[2][8];
#pragma unroll
        for (int k2 = 0; k2 < 2; k2++) {
#pragma unroll
          for (int r = 0; r < 16; r += 2) {
            float p0 = fast_exp2(__builtin_fmaf(sc[k2][r],     CEXP, -mn));
            float p1 = fast_exp2(__builtin_fmaf(sc[k2][r + 1], CEXP, -mn));
            rs0 += p0; rs1 += p1;
            pk2[k2][r >> 1] = pack_bf2_trunc(p0, p1);
          }
        }
        float rs = rs0 + rs1;
        rs += __shfl_xor(rs, 32);
        ls[t2] = ls[t2] * alpha + rs;

        if (__any(alpha != 1.0f)) {
#pragma unroll
          for (int dt = 0; dt < 4; dt++)
#pragma unroll
            for (int r = 0; r < 16; r++) oa[t2][dt][r] *= alpha;
        }

        // ---- PV for this q-subtile: O^T[t2] += V^T @ P^T, P via permlane
        __builtin_amdgcn_s_setprio(1);
#pragma unroll
        for (int ks = 0; ks < 4; ks++) {
          const int k2s = ks >> 1;
          const int sub = (ks & 1) * 4;
          auto w02 = __builtin_amdgcn_permlane32_swap(pk2[k2s][sub + 0], pk2[k2s][sub + 2], false, false);
          auto w13 = __builtin_amdgcn_permlane32_swap(pk2[k2s][sub + 1], pk2[k2s][sub + 3], false, false);
          uint4v pw = (uint4v){(unsigned int)w02[0], (unsigned int)w13[0],
                               (unsigned int)w02[1], (unsigned int)w13[1]};
          bf16x8 pf = __builtin_bit_cast(bf16x8, pw);
          int c = 2 * ks + hi;
#pragma unroll
          for (int dt = 0; dt < 4; dt++) {
            int d = dt * 32 + l31;
            bf16x8 vf = *(const bf16x8*)&Vs[d * 64 + ((c ^ (d & 7)) * 8)];
            oa[t2][dt] = __builtin_amdgcn_mfma_f32_32x32x16_bf16(vf, pf, oa[t2][dt], 0, 0, 0);
          }
        }
        __builtin_amdgcn_s_setprio(0);
      }
    }
  }

  // ---- epilogue: normalize, transpose O^T -> O rows via per-wave LDS patch
  __syncthreads();                 // everyone done reading Ks/Vs
  unsigned short* patch = &S_[w][0];   // [64 q][128 d], chunk-swizzled ^ (q&7)
  float inv[2] = {1.0f / ls[0], 1.0f / ls[1]};
#pragma unroll
  for (int t2 = 0; t2 < 2; t2++) {
    const int qloc = t2 * 32 + l31;
#pragma unroll
    for (int dt = 0; dt < 4; dt++)
#pragma unroll
      for (int rq = 0; rq < 4; rq++) {
        float a0 = oa[t2][dt][rq * 4 + 0] * inv[t2];
        float a1 = oa[t2][dt][rq * 4 + 1] * inv[t2];
        float a2 = oa[t2][dt][rq * 4 + 2] * inv[t2];
        float a3 = oa[t2][dt][rq * 4 + 3] * inv[t2];
        int doff = dt * 32 + 8 * rq + 4 * hi;
        int c = doff >> 3;
        uint2 val = {pack_bf2_rne(a0, a1), pack_bf2_rne(a2, a3)};
        *(uint2*)&patch[qloc * 128 + ((c ^ (qloc & 7)) * 8) + (doff & 7)] = val;
      }
  }
  // in-wave: write -> read dependency handled by compiler waitcnt
#pragma unroll
  for (int it = 0; it < 16; it++) {
    int idx2 = it * 64 + lane;
    int row = idx2 >> 4, c = idx2 & 15;
    int cc = (c & 7) ^ (row & 7);
    int cs = (c & 8) | cc;          // swizzle only low 3 bits (mask was &7)
    ushortx8 vv = *(const ushortx8*)&patch[row * 128 + cs * 8];
    *(ushortx8*)&o[(size_t)(b * SEQ_ + qb + w * 64 + row) * 4096 + h * HD_ + c * 8] = vv;
  }
}

// ---------------------------------------------------------------------------
extern "C" void kernel_launch(void* const* d_in, const int* in_sizes, int n_in,
                              void* d_out, int out_size, void* d_ws, size_t ws_size,
                              hipStream_t stream)
{
  const float* x  = (const float*)d_in[0];
  const float* wq = (const float*)d_in[1];
  const float* wk = (const float*)d_in[2];
  const float* wv = (const float*)d_in[3];
  const float* wo = (const float*)d_in[4];
  const float* fc = (const float*)d_in[5];
  const float* fs = (const float*)d_in[6];
  float* out = (float*)d_out;

  // bf16 workspace layout (2B elems): total 136 MB
  unsigned short* xb    = (unsigned short*)d_ws;                 // 4096x4096 (32MB), reused as ab
  unsigned short* wqkvT = xb    + (size_t)NTOK_ * DIM_;          // 6144x4096 (48MB), reused as woT
  unsigned short* qkvb  = wqkvT + (size_t)QKVW_ * DIM_;          // 4096x6144 (48MB)
  unsigned short* vtb   = qkvb  + (size_t)NTOK_ * QKVW_;         // 8x128x... (8MB)
  unsigned short* ab    = xb;    // alias: xb dead after QKV proj
  unsigned short* woT   = wqkvT; // alias: wqkvT dead after QKV proj

  dim3 blk(256);

  // merged xconv + wtrans3 (region-split grid: 16384 + 24576 blocks)
  prep<<<16384 + 24576, blk, 0, stream>>>(x, xb, wq, wk, wv, wqkvT);

  // fused QKV projection + RoPE epilogue: 24x16 = 384 wgs
  gemm_w16<true, true><<<dim3((QKVW_ / 256) * (NTOK_ / 256)), dim3(1024), 0, stream>>>(
      xb, wqkvT, qkvb, NTOK_, QKVW_, DIM_, fc, fs);

  wtrans<<<dim3(DIM_ / 32, DIM_ / 32), blk, 0, stream>>>(wo, woT, DIM_, DIM_);  // aliases wqkvT: after QKV GEMM

  vtrans2<<<dim3(SEQ_ / 32, HD_ / 32, BSZ_ * NKVH_), blk, 0, stream>>>(qkvb, vtb);

  // flash attention: 1-D LPT-ordered grid (512 blocks)
  flash_attn2<<<dim3((SEQ_ / 256) * NH_ * BSZ_), blk, 0, stream>>>(qkvb, vtb, ab);

  // output projection: 256x256 tiles, 16x16 = 256 wgs (perfect packing)
  gemm_w16<false, false><<<dim3((DIM_ / 256) * (NTOK_ / 256)), dim3(1024), 0, stream>>>(
      ab, woT, out, NTOK_, DIM_, DIM_, nullptr, nullptr);
}